// Round 2
// baseline (10759.960 us; speedup 1.0000x reference)
//
#include <hip/hip_runtime.h>
#include <math.h>

#define BSZ 32
#define TT  32
#define XD  128
#define HD  512
#define VT  2048
#define WD  64
#define RDM 4
#define NDM 1024
#define ET  463
#define GKS 8
#define VKS 16

__device__ __forceinline__ float sigf(float x){ return 1.f/(1.f+expf(-x)); }
__device__ __forceinline__ float logsigf(float x){
    return (x >= 0.f) ? -log1pf(expf(-x)) : x - log1pf(expf(x));
}

__device__ __forceinline__ float blk_sum(float v, float* red){
    int tid = threadIdx.x; red[tid] = v; __syncthreads();
    for (int s = 128; s > 0; s >>= 1){ if (tid < s) red[tid] += red[tid+s]; __syncthreads(); }
    float r = red[0]; __syncthreads(); return r;
}
__device__ __forceinline__ float blk_max(float v, float* red){
    int tid = threadIdx.x; red[tid] = v; __syncthreads();
    for (int s = 128; s > 0; s >>= 1){ if (tid < s) red[tid] = fmaxf(red[tid], red[tid+s]); __syncthreads(); }
    float r = red[0]; __syncthreads(); return r;
}

// ---------------- batchnorm over batch + concat lrv -> layer_in0 (32 x 384) ----------
__global__ void dnc_bn(const float* __restrict__ x, int t,
                       const float* __restrict__ lrv, float* __restrict__ lin0){
    int tid = threadIdx.x;
    if (tid < XD){
        float vals[BSZ];
        float s = 0.f;
        #pragma unroll
        for (int b = 0; b < BSZ; ++b){ vals[b] = x[(b*TT + t)*XD + tid]; s += vals[b]; }
        float mean = s * (1.f/BSZ);
        float ss = 0.f;
        #pragma unroll
        for (int b = 0; b < BSZ; ++b){ float d = vals[b]-mean; ss += d*d; }
        float inv = 1.f / sqrtf(ss*(1.f/BSZ) + 1e-5f);
        #pragma unroll
        for (int b = 0; b < BSZ; ++b) lin0[b*384 + tid] = (vals[b]-mean)*inv;
    }
    for (int idx = tid; idx < BSZ*256; idx += 256){
        int b = idx >> 8, k = idx & 255;
        lin0[b*384 + 128 + k] = lrv[b*256 + k];
    }
}

// ---------------- LSTM pre-activation GEMM: g = in@WihT + h@WhhT (k-split partials) --
// grid (16 jchunks, 2 dirs, GKS), block 256. thread: 4 j x 4 b accumulators.
__global__ void dnc_lstm_gemm(const float* __restrict__ in, int K1,
                              const float* __restrict__ hbase,
                              const float* __restrict__ Wih, const float* __restrict__ Whh,
                              float* __restrict__ gpart){
    const int jc = blockIdx.x, d = blockIdx.y, ks = blockIdx.z;
    const int tid = threadIdx.x;
    const int jg = tid & 31, bg = tid >> 5;
    const int j0 = jc*128 + jg*4;
    const int b0 = bg*4;
    const int cin = K1 >> 6;
    const int nct = (K1 + 512) >> 6;
    const int per = (nct + GKS - 1) / GKS;
    int c0 = ks*per; int c1 = min(nct, c0+per);
    __shared__ __align__(16) float tile[64*36];
    float acc[4][4] = {{0}};
    for (int c = c0; c < c1; ++c){
        const float* src; int stride, kb; const float* Wb; int Kw;
        if (c < cin){ src = in; stride = K1; kb = c*64; Wb = Wih + (size_t)d*2048*K1; Kw = K1; }
        else { src = hbase + d*(BSZ*HD); stride = HD; kb = (c-cin)*64; Wb = Whh + (size_t)d*2048*512; Kw = 512; }
        #pragma unroll
        for (int i = 0; i < 8; ++i){
            int idx = i*256 + tid; int kk = idx & 63, b = idx >> 6;
            tile[kk*36 + b] = src[b*stride + kb + kk];
        }
        __syncthreads();
        const float* w0p = Wb + (size_t)(j0+0)*Kw + kb;
        const float* w1p = Wb + (size_t)(j0+1)*Kw + kb;
        const float* w2p = Wb + (size_t)(j0+2)*Kw + kb;
        const float* w3p = Wb + (size_t)(j0+3)*Kw + kb;
        #pragma unroll
        for (int kk = 0; kk < 64; kk += 4){
            float4 a0 = *(const float4*)&tile[(kk+0)*36 + b0];
            float4 a1 = *(const float4*)&tile[(kk+1)*36 + b0];
            float4 a2 = *(const float4*)&tile[(kk+2)*36 + b0];
            float4 a3 = *(const float4*)&tile[(kk+3)*36 + b0];
            float4 w;
            #define ACCJ(JJ, WP) \
                w = *(const float4*)(WP + kk); \
                acc[JJ][0] += a0.x*w.x + a1.x*w.y + a2.x*w.z + a3.x*w.w; \
                acc[JJ][1] += a0.y*w.x + a1.y*w.y + a2.y*w.z + a3.y*w.w; \
                acc[JJ][2] += a0.z*w.x + a1.z*w.y + a2.z*w.z + a3.z*w.w; \
                acc[JJ][3] += a0.w*w.x + a1.w*w.y + a2.w*w.z + a3.w*w.w;
            ACCJ(0, w0p) ACCJ(1, w1p) ACCJ(2, w2p) ACCJ(3, w3p)
            #undef ACCJ
        }
        __syncthreads();
    }
    #pragma unroll
    for (int jj = 0; jj < 4; ++jj){
        #pragma unroll
        for (int bb = 0; bb < 4; ++bb)
            gpart[((size_t)(d*GKS + ks)*BSZ + (b0+bb))*2048 + (j0+jj)] = acc[jj][bb];
    }
}

// ---------------- LSTM gates -> h, c (also writes flat, optional next-layer input) ---
__global__ void dnc_gates(const float* __restrict__ gpart,
                          const float* __restrict__ bih, const float* __restrict__ bhh,
                          float* __restrict__ cstate, float* __restrict__ hstate,
                          float* __restrict__ flat, float* __restrict__ lout, int l){
    int idx = blockIdx.x*256 + threadIdx.x;
    int u = idx & 511, b = (idx >> 9) & 31, d = idx >> 14;
    int cell = 2*l + d;
    float g[4];
    #pragma unroll
    for (int xg = 0; xg < 4; ++xg){
        int j = xg*512 + u;
        float s = bih[d*2048 + j] + bhh[d*2048 + j];
        #pragma unroll
        for (int ks = 0; ks < GKS; ++ks)
            s += gpart[((size_t)(d*GKS + ks)*BSZ + b)*2048 + j];
        g[xg] = s;
    }
    float ig = sigf(g[0]), fg = sigf(g[1]), og = sigf(g[3]);
    float gg = tanhf(g[2]);
    int ci = (cell*BSZ + b)*HD + u;
    float c2 = fg*cstate[ci] + ig*gg;
    cstate[ci] = c2;
    float h = og*tanhf(c2);
    hstate[ci] = h;
    flat[b*2048 + cell*HD + u] = h;
    if (lout) lout[b*1024 + d*HD + u] = h;
}

// ---------------- generic GEMV: out[b][m] = sum_k flat[b][k]*Wm[k][m] (k-split) ------
// grid (mchunks, VKS), block 256. thread: 2 m x 8 b.
__global__ void dnc_gemv(const float* __restrict__ fin, const float* __restrict__ Wm,
                         int Mdim, float* __restrict__ outp){
    const int mb = blockIdx.x, ksi = blockIdx.y;
    const int tid = threadIdx.x;
    const int lane = tid & 63, bg = tid >> 6;
    const int b0 = bg*8;
    const int m0 = mb*128 + lane, m1 = m0 + 64;
    const int k0 = ksi*128;
    __shared__ __align__(16) float tile[128*36];
    #pragma unroll
    for (int i = 0; i < 16; ++i){
        int idx = i*256 + tid; int kk = idx & 127, b = idx >> 7;
        tile[kk*36 + b] = fin[b*2048 + k0 + kk];
    }
    __syncthreads();
    bool v0 = m0 < Mdim, v1 = m1 < Mdim;
    float acc[16] = {0};
    for (int kk = 0; kk < 128; ++kk){
        float4 pq = *(const float4*)&tile[kk*36 + b0];
        float4 qq = *(const float4*)&tile[kk*36 + b0 + 4];
        const float* wr = Wm + (size_t)(k0+kk)*Mdim;
        float w0 = v0 ? wr[m0] : 0.f;
        float w1 = v1 ? wr[m1] : 0.f;
        acc[0]+=pq.x*w0; acc[1]+=pq.y*w0; acc[2]+=pq.z*w0; acc[3]+=pq.w*w0;
        acc[4]+=qq.x*w0; acc[5]+=qq.y*w0; acc[6]+=qq.z*w0; acc[7]+=qq.w*w0;
        acc[8]+=pq.x*w1; acc[9]+=pq.y*w1; acc[10]+=pq.z*w1; acc[11]+=pq.w*w1;
        acc[12]+=qq.x*w1; acc[13]+=qq.y*w1; acc[14]+=qq.z*w1; acc[15]+=qq.w*w1;
    }
    if (v0){
        #pragma unroll
        for (int bb = 0; bb < 8; ++bb)
            outp[((size_t)ksi*BSZ + b0+bb)*Mdim + m0] = acc[bb];
    }
    if (v1){
        #pragma unroll
        for (int bb = 0; bb < 8; ++bb)
            outp[((size_t)ksi*BSZ + b0+bb)*Mdim + m1] = acc[8+bb];
    }
}

// ---------------- layernorm over E_t (sums VKS partials) ----------------------------
__global__ void dnc_ln(const float* __restrict__ ep, float* __restrict__ iv){
    int b = blockIdx.x, tid = threadIdx.x;
    __shared__ float buf[ET];
    __shared__ float red[256];
    float ls = 0.f;
    for (int m = tid; m < ET; m += 256){
        float v = 0.f;
        #pragma unroll
        for (int s = 0; s < VKS; ++s) v += ep[((size_t)s*BSZ + b)*ET + m];
        buf[m] = v; ls += v;
    }
    float mean = blk_sum(ls, red) * (1.f/ET);
    float lss = 0.f;
    for (int m = tid; m < ET; m += 256){ float d = buf[m]-mean; lss += d*d; }
    float var = blk_sum(lss, red) * (1.f/ET);
    float rinv = 1.f / sqrtf(var + 1e-5f);
    for (int m = tid; m < ET; m += 256) iv[b*ET + m] = (buf[m]-mean)*rinv;
}

// ---------------- usage update ------------------------------------------------------
__global__ void dnc_usage(const float* __restrict__ iv, const float* __restrict__ lrw,
                          const float* __restrict__ lww, float* __restrict__ ubuf){
    int idx = blockIdx.x*256 + threadIdx.x;
    int b = idx >> 10;
    float4 lw4 = *(const float4*)&lrw[(size_t)idx*4];
    float f0 = sigf(iv[b*ET + 453]);
    float f1 = sigf(iv[b*ET + 454]);
    float f2 = sigf(iv[b*ET + 455]);
    float f3 = sigf(iv[b*ET + 456]);
    float ret = (1.f - f0*lw4.x) * (1.f - f1*lw4.y) * (1.f - f2*lw4.z) * (1.f - f3*lw4.w);
    float u = ubuf[idx], lw = lww[idx];
    ubuf[idx] = (u + lw - u*lw) * ret;
}

// ---------------- stable argsort + allocation weighting -----------------------------
__global__ __launch_bounds__(1024) void dnc_sort_alloc(const float* __restrict__ ubuf,
                                                       float* __restrict__ allocw){
    int b = blockIdx.x, tid = threadIdx.x;
    __shared__ unsigned long long keys[1024];
    __shared__ float pa[1024], pb[1024];
    unsigned int bits = __float_as_uint(ubuf[b*1024 + tid]);
    keys[tid] = ((unsigned long long)bits << 32) | (unsigned int)tid;
    __syncthreads();
    for (int k = 2; k <= 1024; k <<= 1){
        for (int j = k >> 1; j > 0; j >>= 1){
            int ixj = tid ^ j;
            if (ixj > tid){
                unsigned long long a = keys[tid], c = keys[ixj];
                bool up = ((tid & k) == 0);
                if ((a > c) == up){ keys[tid] = c; keys[ixj] = a; }
            }
            __syncthreads();
        }
    }
    unsigned long long kv = keys[tid];
    float su = __uint_as_float((unsigned int)(kv >> 32));
    int idxv = (int)(kv & 0xffffffffu);
    pa[tid] = su;
    __syncthreads();
    float* s = pa; float* d = pb;
    for (int off = 1; off < 1024; off <<= 1){
        float v = s[tid]; if (tid >= off) v *= s[tid - off];
        d[tid] = v; __syncthreads();
        float* t2 = s; s = d; d = t2;
    }
    float cp = (tid == 0) ? 1.f : s[tid-1];
    allocw[b*1024 + idxv] = (1.f - su) * cp;
}

// ---------------- content write score -----------------------------------------------
__global__ void dnc_cw_score(const float* __restrict__ M, const float* __restrict__ iv,
                             float* __restrict__ scw){
    int b = blockIdx.x, tid = threadIdx.x;
    int n = blockIdx.y*256 + tid;
    __shared__ float key[64];
    if (tid < 64) key[tid] = iv[b*ET + 260 + tid];
    __syncthreads();
    float ksq = 0.f;
    #pragma unroll
    for (int w = 0; w < 64; ++w) ksq += key[w]*key[w];
    float kden = sqrtf(ksq) + 1e-8f;
    float wb = 1.f - logsigf(iv[b*ET + 324]);
    const float* Mrow = M + ((size_t)b*1024 + n)*64;
    float dot = 0.f, msq = 0.f;
    #pragma unroll
    for (int w = 0; w < 64; w += 4){
        float4 mv = *(const float4*)(Mrow + w);
        dot += mv.x*key[w] + mv.y*key[w+1] + mv.z*key[w+2] + mv.w*key[w+3];
        msq += mv.x*mv.x + mv.y*mv.y + mv.z*mv.z + mv.w*mv.w;
    }
    scw[b*1024 + n] = wb * dot / ((sqrtf(msq) + 1e-8f) * kden);
}

// ---------------- content write softmax + ww ----------------------------------------
__global__ void dnc_cw_ww(const float* __restrict__ scw, const float* __restrict__ allocw,
                          const float* __restrict__ iv, float* __restrict__ lww){
    int b = blockIdx.x, tid = threadIdx.x;
    __shared__ float red[256];
    float v[4];
    #pragma unroll
    for (int i = 0; i < 4; ++i) v[i] = scw[b*1024 + i*256 + tid];
    float mx = fmaxf(fmaxf(v[0],v[1]), fmaxf(v[2],v[3]));
    mx = blk_max(mx, red);
    float ls = 0.f;
    #pragma unroll
    for (int i = 0; i < 4; ++i) ls += expf(v[i]-mx);
    float tot = blk_sum(ls, red);
    float wg = sigf(iv[b*ET + 458]);
    float ag = sigf(iv[b*ET + 457]);
    #pragma unroll
    for (int i = 0; i < 4; ++i){
        int n = i*256 + tid;
        float cw = expf(v[i]-mx) / tot;
        lww[b*1024 + n] = wg * (ag*allocw[b*1024 + n] + (1.f-ag)*cw);
    }
}

// ---------------- memory update + row norms -----------------------------------------
__global__ void dnc_memup(float* __restrict__ M, const float* __restrict__ lww,
                          const float* __restrict__ iv, float* __restrict__ Mnorm){
    int row = blockIdx.x*4 + (threadIdx.x >> 6);
    int w = threadIdx.x & 63;
    int b = row >> 10;
    float wwv = lww[row];
    float er = sigf(iv[b*ET + 325 + w]);
    float wv = iv[b*ET + 389 + w];
    size_t mi = (size_t)row*64 + w;
    float m = M[mi];
    float mn = m*(1.f - wwv*er) + wwv*wv;
    M[mi] = mn;
    float s = mn*mn;
    #pragma unroll
    for (int off = 32; off > 0; off >>= 1) s += __shfl_xor(s, off);
    if (w == 0) Mnorm[row] = sqrtf(s);
}

// ---------------- read scores --------------------------------------------------------
__global__ void dnc_rd_score(const float* __restrict__ M, const float* __restrict__ Mnorm,
                             const float* __restrict__ iv, float* __restrict__ scr){
    int b = blockIdx.x, tid = threadIdx.x;
    int n = blockIdx.y*256 + tid;
    __shared__ float rkn[256];
    __shared__ float nrm[4];
    rkn[tid & 255] = iv[b*ET + tid];   // rkeys[w][r] at offset w*4+r == tid
    __syncthreads();
    if (tid < 4){
        float s = 0.f;
        #pragma unroll
        for (int w = 0; w < 64; ++w){ float v = rkn[w*4 + tid]; s += v*v; }
        nrm[tid] = sqrtf(s) + 1e-8f;
    }
    __syncthreads();
    float scaled = rkn[tid] / nrm[tid & 3];
    __syncthreads();
    rkn[tid] = scaled;
    __syncthreads();
    float rb[4];
    #pragma unroll
    for (int r = 0; r < 4; ++r) rb[r] = 1.f - logsigf(iv[b*ET + 256 + r]);
    const float* Mrow = M + ((size_t)b*1024 + n)*64;
    float dot[4] = {0,0,0,0};
    #pragma unroll
    for (int w = 0; w < 64; w += 4){
        float4 mv = *(const float4*)(Mrow + w);
        #pragma unroll
        for (int r = 0; r < 4; ++r)
            dot[r] += mv.x*rkn[w*4+r] + mv.y*rkn[(w+1)*4+r] + mv.z*rkn[(w+2)*4+r] + mv.w*rkn[(w+3)*4+r];
    }
    float den = Mnorm[b*1024 + n] + 1e-8f;
    #pragma unroll
    for (int r = 0; r < 4; ++r) scr[((size_t)(b*4 + r))*1024 + n] = rb[r]*dot[r]/den;
}

// ---------------- read softmax -> rw -------------------------------------------------
__global__ void dnc_rd_sm(const float* __restrict__ scr, float* __restrict__ lrw){
    int br = blockIdx.x, tid = threadIdx.x;
    int b = br >> 2, r = br & 3;
    __shared__ float red[256];
    float v[4];
    #pragma unroll
    for (int i = 0; i < 4; ++i) v[i] = scr[(size_t)br*1024 + i*256 + tid];
    float mx = fmaxf(fmaxf(v[0],v[1]), fmaxf(v[2],v[3]));
    mx = blk_max(mx, red);
    float ls = 0.f;
    #pragma unroll
    for (int i = 0; i < 4; ++i) ls += expf(v[i]-mx);
    float tot = blk_sum(ls, red);
    #pragma unroll
    for (int i = 0; i < 4; ++i){
        int n = i*256 + tid;
        lrw[((size_t)b*1024 + n)*4 + r] = expf(v[i]-mx)/tot;
    }
}

// ---------------- read vectors (n-split partials) -----------------------------------
__global__ void dnc_rv(const float* __restrict__ M, const float* __restrict__ lrw,
                       float* __restrict__ rvp){
    int b = blockIdx.x, ns = blockIdx.y;
    int r = threadIdx.x >> 6, w = threadIdx.x & 63;
    float acc = 0.f;
    for (int i = 0; i < 256; ++i){
        int n = ns*256 + i;
        acc += M[((size_t)b*1024 + n)*64 + w] * lrw[((size_t)b*1024 + n)*4 + r];
    }
    rvp[((size_t)(ns*BSZ + b))*256 + r*64 + w] = acc;
}

__global__ void dnc_rv_fin(const float* __restrict__ rvp, float* __restrict__ lrv){
    int b = blockIdx.x, tid = threadIdx.x;
    int w = tid >> 2, r = tid & 3;
    float s = 0.f;
    #pragma unroll
    for (int ns = 0; ns < 4; ++ns) s += rvp[((size_t)(ns*BSZ + b))*256 + r*64 + w];
    lrv[b*256 + tid] = s;   // layout [b][w*4+r]
}

// ---------------- rv @ Wr partials ---------------------------------------------------
__global__ void dnc_ywr(const float* __restrict__ lrv, const float* __restrict__ Wr,
                        float* __restrict__ ywrp){
    int mb = blockIdx.x, ks = blockIdx.y, tid = threadIdx.x;
    int m = mb*256 + tid, k0 = ks*64;
    __shared__ float rvf[32*64];
    #pragma unroll
    for (int i = 0; i < 8; ++i){
        int idx = i*256 + tid; int b = idx >> 6, kk = idx & 63;
        rvf[b*64 + kk] = lrv[b*256 + k0 + kk];
    }
    __syncthreads();
    float acc[32];
    #pragma unroll
    for (int b = 0; b < 32; ++b) acc[b] = 0.f;
    for (int kk = 0; kk < 64; ++kk){
        float wv = Wr[(size_t)(k0+kk)*VT + m];
        #pragma unroll
        for (int b = 0; b < 32; ++b) acc[b] += rvf[b*64 + kk]*wv;
    }
    #pragma unroll
    for (int b = 0; b < 32; ++b) ywrp[((size_t)(ks*BSZ + b))*VT + m] = acc[b];
}

// ---------------- final: yt = sum partials; out = max over t -------------------------
__global__ void dnc_yt_fin(const float* __restrict__ vtp, const float* __restrict__ ywrp,
                           float* __restrict__ out, int t){
    int idx = blockIdx.x*256 + threadIdx.x;
    int b = idx >> 11, m = idx & 2047;
    float acc = 0.f;
    #pragma unroll
    for (int s = 0; s < VKS; ++s) acc += vtp[((size_t)s*BSZ + b)*VT + m];
    #pragma unroll
    for (int ks = 0; ks < 4; ++ks) acc += ywrp[((size_t)(ks*BSZ + b))*VT + m];
    if (t == 0) out[idx] = acc;
    else out[idx] = fmaxf(out[idx], acc);
}

extern "C" void kernel_launch(void* const* d_in, const int* in_sizes, int n_in,
                              void* d_out, int out_size, void* d_ws, size_t ws_size,
                              hipStream_t stream){
    const float* x      = (const float*)d_in[0];
    const float* mem0   = (const float*)d_in[1];
    const float* Wy     = (const float*)d_in[2];
    const float* WE     = (const float*)d_in[3];
    const float* Wr     = (const float*)d_in[4];
    const float* Wih0   = (const float*)d_in[5];
    const float* Whh0   = (const float*)d_in[6];
    const float* bih0   = (const float*)d_in[7];
    const float* bhh0   = (const float*)d_in[8];
    const float* Wih1   = (const float*)d_in[9];
    const float* Whh1   = (const float*)d_in[10];
    const float* bih1   = (const float*)d_in[11];
    const float* bhh1   = (const float*)d_in[12];
    float* out = (float*)d_out;

    float* p = (float*)d_ws;
    float* M      = p; p += (size_t)32*1024*64;
    float* Mnorm  = p; p += 32*1024;
    float* hstate = p; p += 4*32*512;     // zero block start
    float* cstate = p; p += 4*32*512;
    float* ubuf   = p; p += 32*1024;
    float* lww    = p; p += 32*1024;
    float* lrw    = p; p += 32*1024*4;
    float* lrv    = p; p += 32*256;       // zero block end
    float* lin0   = p; p += 32*384;
    float* lin1   = p; p += 32*1024;
    float* gpart  = p; p += (size_t)2*GKS*32*2048;
    float* flat   = p; p += 32*2048;
    float* vtp    = p; p += (size_t)VKS*32*2048;
    float* ep     = p; p += (size_t)VKS*32*ET;
    float* iv     = p; p += 32*ET;
    float* allocw = p; p += 32*1024;
    float* scw    = p; p += 32*1024;
    float* scr    = p; p += 32*4*1024;
    float* rvp    = p; p += 4*32*256;
    float* ywrp   = p; p += (size_t)4*32*2048;

    (void)hipMemcpyAsync(M, mem0, (size_t)32*1024*64*sizeof(float), hipMemcpyDeviceToDevice, stream);
    size_t zfloats = (size_t)(4*32*512)*2 + 32*1024*2 + 32*1024*4 + 32*256;
    (void)hipMemsetAsync(hstate, 0, zfloats*sizeof(float), stream);

    for (int t = 0; t < TT; ++t){
        dnc_bn<<<1, 256, 0, stream>>>(x, t, lrv, lin0);
        dnc_lstm_gemm<<<dim3(16,2,GKS), 256, 0, stream>>>(lin0, 384, hstate, Wih0, Whh0, gpart);
        dnc_gates<<<128, 256, 0, stream>>>(gpart, bih0, bhh0, cstate, hstate, flat, lin1, 0);
        dnc_lstm_gemm<<<dim3(16,2,GKS), 256, 0, stream>>>(lin1, 1024, hstate + 2*32*512, Wih1, Whh1, gpart);
        dnc_gates<<<128, 256, 0, stream>>>(gpart, bih1, bhh1, cstate, hstate, flat, nullptr, 1);
        dnc_gemv<<<dim3(16,VKS), 256, 0, stream>>>(flat, Wy, 2048, vtp);
        dnc_gemv<<<dim3(4,VKS), 256, 0, stream>>>(flat, WE, ET, ep);
        dnc_ln<<<32, 256, 0, stream>>>(ep, iv);
        dnc_usage<<<128, 256, 0, stream>>>(iv, lrw, lww, ubuf);
        dnc_sort_alloc<<<32, 1024, 0, stream>>>(ubuf, allocw);
        dnc_cw_score<<<dim3(32,4), 256, 0, stream>>>(M, iv, scw);
        dnc_cw_ww<<<32, 256, 0, stream>>>(scw, allocw, iv, lww);
        dnc_memup<<<8192, 256, 0, stream>>>(M, lww, iv, Mnorm);
        dnc_rd_score<<<dim3(32,4), 256, 0, stream>>>(M, Mnorm, iv, scr);
        dnc_rd_sm<<<128, 256, 0, stream>>>(scr, lrw);
        dnc_rv<<<dim3(32,4), 256, 0, stream>>>(M, lrw, rvp);
        dnc_rv_fin<<<32, 256, 0, stream>>>(rvp, lrv);
        dnc_ywr<<<dim3(8,4), 256, 0, stream>>>(lrv, Wr, ywrp);
        dnc_yt_fin<<<256, 256, 0, stream>>>(vtp, ywrp, out, t);
    }
}